// Round 6
// baseline (473.356 us; speedup 1.0000x reference)
//
#include <hip/hip_runtime.h>

typedef float     v2f __attribute__((ext_vector_type(2)));
typedef _Float16  v2h __attribute__((ext_vector_type(2)));
typedef unsigned int uint;

#define BB 2048
#define TT 1024
#define CC 9
#define HH 36
#define CSTEPS 64                 // timesteps per x-chunk
#define CF (CSTEPS * CC)          // 576 floats per chunk
#define NCH (TT / CSTEPS)         // 16 chunks

__device__ __forceinline__ void pin2f(v2f& v) {
    uint64_t t = __builtin_bit_cast(uint64_t, v);
    asm volatile("" : "+v"(t));
    v = __builtin_bit_cast(v2f, t);
}
__device__ __forceinline__ void pinh(v2h& v) {
    uint t = __builtin_bit_cast(uint, v);
    asm volatile("" : "+v"(t));
    v = __builtin_bit_cast(v2h, t);
}

// async global->LDS, 4 B per lane (wave writes 256 B: lds_base + lane*4)
__device__ __forceinline__ void gload4(const float* g, float* l) {
    __builtin_amdgcn_global_load_lds(
        (const __attribute__((address_space(1))) unsigned int*)g,
        (__attribute__((address_space(3))) unsigned int*)l,
        4, 0, 0);
}

// One wave per batch element. Lane j < 36 owns hidden j. h-path in fp16
// (v_dot2_f32_f16, f32 accumulate) so all weights fit in arch VGPRs
// (R3 failure: 190 f32 live values -> AGPR parking -> ~135 moves/step).
// x staged 64 steps ahead in LDS via global_load_lds (R3, kept).
__global__ __launch_bounds__(64, 2) void gru_kernel(
    const float* __restrict__ x,      // (B,T,C)
    const float* __restrict__ w_ih,   // (3H,C)
    const float* __restrict__ w_hh,   // (3H,H)
    const float* __restrict__ b_ih,   // (3H)
    const float* __restrict__ b_hh,   // (3H)
    const float* __restrict__ w_head, // (1,H)
    const float* __restrict__ b_head, // (1)
    float* __restrict__ out)          // (B,1)
{
    const int b = blockIdx.x;
    const int j = threadIdx.x;

    __shared__ __align__(16) uint hbuf32[20];       // h as 18 half2 words (+pad)
    __shared__ __align__(16) float xlds[2][CF];     // x chunk double buffer

    // ---- per-lane weights (lane >= 36 loads row 0; values never escape) ----
    const int jj = (j < HH) ? j : 0;
    v2h wrh[18], wzh[18], wnh[18];    // w_hh rows, fp16 pairs
    v2f wri[4], wzi[4], wni[4];       // w_ih rows, f32 pairs
    float wri8, wzi8, wni8, br, bz, bni, bnh;
    {
        const float* pr = w_hh + (size_t)jj * HH;
        const float* pz = w_hh + (size_t)(HH + jj) * HH;
        const float* pn = w_hh + (size_t)(2 * HH + jj) * HH;
#pragma unroll
        for (int k = 0; k < 18; ++k) {
            wrh[k] = (v2h){(_Float16)pr[2*k], (_Float16)pr[2*k+1]};
            wzh[k] = (v2h){(_Float16)pz[2*k], (_Float16)pz[2*k+1]};
            wnh[k] = (v2h){(_Float16)pn[2*k], (_Float16)pn[2*k+1]};
        }
        const float* qr = w_ih + (size_t)jj * CC;
        const float* qz = w_ih + (size_t)(HH + jj) * CC;
        const float* qn = w_ih + (size_t)(2 * HH + jj) * CC;
#pragma unroll
        for (int p = 0; p < 4; ++p) {
            wri[p] = (v2f){qr[2*p], qr[2*p+1]};
            wzi[p] = (v2f){qz[2*p], qz[2*p+1]};
            wni[p] = (v2f){qn[2*p], qn[2*p+1]};
        }
        wri8 = qr[8]; wzi8 = qz[8]; wni8 = qn[8];
        br  = b_ih[jj] + b_hh[jj];
        bz  = b_ih[HH + jj] + b_hh[HH + jj];
        bni = b_ih[2 * HH + jj];
        bnh = b_hh[2 * HH + jj];
    }
    // ---- pin: loads may not be sunk/rematerialized into the loop ----
#pragma unroll
    for (int k = 0; k < 18; ++k) { pinh(wrh[k]); pinh(wzh[k]); pinh(wnh[k]); }
#pragma unroll
    for (int p = 0; p < 4; ++p) { pin2f(wri[p]); pin2f(wzi[p]); pin2f(wni[p]); }
    asm volatile("" : "+v"(wri8), "+v"(wzi8), "+v"(wni8));
    asm volatile("" : "+v"(br), "+v"(bz), "+v"(bni), "+v"(bnh));

    const float* xg = x + (size_t)b * (TT * CC);

    // prefetch chunk 0
#pragma unroll
    for (int k = 0; k < 9; ++k) gload4(xg + k * 64 + j, &xlds[0][k * 64]);

    v2h h2[18];
#pragma unroll
    for (int k = 0; k < 18; ++k) h2[k] = (v2h){(_Float16)0.f, (_Float16)0.f};
    float h_own = 0.f;

    for (int c = 0; c < NCH; ++c) {
        asm volatile("s_waitcnt vmcnt(0)" ::: "memory");
        __builtin_amdgcn_sched_barrier(0);
        if (c + 1 < NCH) {
            const float* src = xg + (size_t)(c + 1) * CF;
            float* dst = &xlds[(c + 1) & 1][0];
#pragma unroll
            for (int k = 0; k < 9; ++k) gload4(src + k * 64 + j, dst + k * 64);
        }
        const float* xc = &xlds[c & 1][0];

#pragma unroll 2
        for (int s = 0; s < CSTEPS; ++s) {
            const float* xs = xc + s * CC;
            float xv[CC];
#pragma unroll
            for (int cc = 0; cc < CC; ++cc) xv[cc] = xs[cc];

            // x-part (f32): init with biases
            v2f axr = (v2f){br,  0.f};
            v2f axz = (v2f){bz,  0.f};
            v2f axn = (v2f){bni, 0.f};
#pragma unroll
            for (int p = 0; p < 4; ++p) {
                v2f xp2 = (v2f){xv[2*p], xv[2*p+1]};
                axr = __builtin_elementwise_fma(wri[p], xp2, axr);
                axz = __builtin_elementwise_fma(wzi[p], xp2, axz);
                axn = __builtin_elementwise_fma(wni[p], xp2, axn);
            }
            float sr = fmaf(wri8, xv[8], axr.x + axr.y);
            float sz = fmaf(wzi8, xv[8], axz.x + axz.y);
            float sn = fmaf(wni8, xv[8], axn.x + axn.y);
            float gn = bnh;

            // h-part: fp16 dot2 with f32 accumulation
#pragma unroll
            for (int k = 0; k < 18; ++k) {
                sr = __builtin_amdgcn_fdot2(wrh[k], h2[k], sr, false);
                sz = __builtin_amdgcn_fdot2(wzh[k], h2[k], sz, false);
                gn = __builtin_amdgcn_fdot2(wnh[k], h2[k], gn, false);
            }

            float r = __builtin_amdgcn_rcpf(1.f + __expf(-sr));
            float z = __builtin_amdgcn_rcpf(1.f + __expf(-sz));
            float a = sn + r * gn;
            float n = 1.f - 2.f * __builtin_amdgcn_rcpf(__expf(2.f * a) + 1.f);
            h_own = z * (h_own - n) + n;

            // broadcast h_t as packed half2 words (1-wave block: DS per-wave
            // ordering, no barrier needed)
            float nb = __shfl_xor(h_own, 1);
            if (((j & 1) == 0) && (j < HH)) {
                hbuf32[j >> 1] = __builtin_bit_cast(
                    uint, __builtin_amdgcn_cvt_pkrtz(h_own, nb));
            }
            {
#pragma unroll
                for (int q = 0; q < 4; ++q) {
                    uint4 t4 = ((const uint4*)hbuf32)[q];
                    h2[4*q+0] = __builtin_bit_cast(v2h, t4.x);
                    h2[4*q+1] = __builtin_bit_cast(v2h, t4.y);
                    h2[4*q+2] = __builtin_bit_cast(v2h, t4.z);
                    h2[4*q+3] = __builtin_bit_cast(v2h, t4.w);
                }
                uint2 t2 = ((const uint2*)hbuf32)[8];
                h2[16] = __builtin_bit_cast(v2h, t2.x);
                h2[17] = __builtin_bit_cast(v2h, t2.y);
            }
        }
    }

    // head: out[b] = sum_j h[j] * w_head[j] + b_head
    float whead = (j < HH) ? w_head[j] : 0.f;
    float v = (j < HH) ? h_own * whead : 0.f;
#pragma unroll
    for (int off = 32; off; off >>= 1) v += __shfl_down(v, off);
    if (j == 0) out[b] = v + b_head[0];
}

extern "C" void kernel_launch(void* const* d_in, const int* in_sizes, int n_in,
                              void* d_out, int out_size, void* d_ws, size_t ws_size,
                              hipStream_t stream) {
    const float* x      = (const float*)d_in[0];
    const float* w_ih   = (const float*)d_in[1];
    const float* w_hh   = (const float*)d_in[2];
    const float* b_ih   = (const float*)d_in[3];
    const float* b_hh   = (const float*)d_in[4];
    const float* w_head = (const float*)d_in[5];
    const float* b_head = (const float*)d_in[6];
    float* out = (float*)d_out;

    gru_kernel<<<BB, 64, 0, stream>>>(x, w_ih, w_hh, b_ih, b_hh,
                                      w_head, b_head, out);
}

// Round 7
// 402.788 us; speedup vs baseline: 1.1752x; 1.1752x over previous
//
#include <hip/hip_runtime.h>

typedef float     v2f __attribute__((ext_vector_type(2)));
typedef _Float16  v2h __attribute__((ext_vector_type(2)));
typedef unsigned int uint;

#define BB 2048
#define TT 1024
#define CC 9
#define HH 36
#define CSTEPS 64                 // timesteps per x-chunk
#define CF (CSTEPS * CC)          // 576 floats per chunk
#define NCH (TT / CSTEPS)         // 16 chunks

__device__ __forceinline__ void pin2f(v2f& v) {
    uint64_t t = __builtin_bit_cast(uint64_t, v);
    asm volatile("" : "+v"(t));
    v = __builtin_bit_cast(v2f, t);
}
__device__ __forceinline__ void pinh(v2h& v) {
    uint t = __builtin_bit_cast(uint, v);
    asm volatile("" : "+v"(t));
    v = __builtin_bit_cast(v2h, t);
}

// async global->LDS, 4 B per lane (wave writes 256 B: lds_base + lane*4)
__device__ __forceinline__ void gload4(const float* g, float* l) {
    __builtin_amdgcn_global_load_lds(
        (const __attribute__((address_space(1))) unsigned int*)g,
        (__attribute__((address_space(3))) unsigned int*)l,
        4, 0, 0);
}

// One wave per batch element. Lane j < 36 owns hidden j. h-path fp16
// (v_dot2_f32_f16, f32 accum). waves_per_eu(2,2) pins the occupancy target
// so the allocator gets a true 256-VGPR budget and stops parking pinned
// weights in AGPRs (R3/R5 failure: v_accvgpr shuttles every step).
__global__ __launch_bounds__(64)
__attribute__((amdgpu_waves_per_eu(2, 2)))
void gru_kernel(
    const float* __restrict__ x,      // (B,T,C)
    const float* __restrict__ w_ih,   // (3H,C)
    const float* __restrict__ w_hh,   // (3H,H)
    const float* __restrict__ b_ih,   // (3H)
    const float* __restrict__ b_hh,   // (3H)
    const float* __restrict__ w_head, // (1,H)
    const float* __restrict__ b_head, // (1)
    float* __restrict__ out)          // (B,1)
{
    const int b = blockIdx.x;
    const int j = threadIdx.x;

    __shared__ __align__(16) _Float16 hbuf16[64];   // h bcast, 64-wide (no branch)
    __shared__ __align__(16) float xlds[2][CF];     // x chunk double buffer

    // ---- per-lane weights (lane >= 36 loads row 0; values never escape) ----
    const int jj = (j < HH) ? j : 0;
    v2h wrh[18], wzh[18], wnh[18];    // w_hh rows, fp16 pairs
    v2f wri[4], wzi[4], wni[4];       // w_ih rows, f32 pairs
    float wri8, wzi8, wni8, br, bz, bni, bnh;
    {
        const float* pr = w_hh + (size_t)jj * HH;
        const float* pz = w_hh + (size_t)(HH + jj) * HH;
        const float* pn = w_hh + (size_t)(2 * HH + jj) * HH;
#pragma unroll
        for (int k = 0; k < 18; ++k) {
            wrh[k] = (v2h){(_Float16)pr[2*k], (_Float16)pr[2*k+1]};
            wzh[k] = (v2h){(_Float16)pz[2*k], (_Float16)pz[2*k+1]};
            wnh[k] = (v2h){(_Float16)pn[2*k], (_Float16)pn[2*k+1]};
        }
        const float* qr = w_ih + (size_t)jj * CC;
        const float* qz = w_ih + (size_t)(HH + jj) * CC;
        const float* qn = w_ih + (size_t)(2 * HH + jj) * CC;
#pragma unroll
        for (int p = 0; p < 4; ++p) {
            wri[p] = (v2f){qr[2*p], qr[2*p+1]};
            wzi[p] = (v2f){qz[2*p], qz[2*p+1]};
            wni[p] = (v2f){qn[2*p], qn[2*p+1]};
        }
        wri8 = qr[8]; wzi8 = qz[8]; wni8 = qn[8];
        br  = b_ih[jj] + b_hh[jj];
        bz  = b_ih[HH + jj] + b_hh[HH + jj];
        bni = b_ih[2 * HH + jj];
        bnh = b_hh[2 * HH + jj];
    }
    // ---- pin: loads may not be sunk/rematerialized into the loop ----
#pragma unroll
    for (int k = 0; k < 18; ++k) { pinh(wrh[k]); pinh(wzh[k]); pinh(wnh[k]); }
#pragma unroll
    for (int p = 0; p < 4; ++p) { pin2f(wri[p]); pin2f(wzi[p]); pin2f(wni[p]); }
    asm volatile("" : "+v"(wri8), "+v"(wzi8), "+v"(wni8));
    asm volatile("" : "+v"(br), "+v"(bz), "+v"(bni), "+v"(bnh));

    const float* xg = x + (size_t)b * (TT * CC);

    // prefetch chunk 0
#pragma unroll
    for (int k = 0; k < 9; ++k) gload4(xg + k * 64 + j, &xlds[0][k * 64]);

    v2h h2[18];
#pragma unroll
    for (int k = 0; k < 18; ++k) h2[k] = (v2h){(_Float16)0.f, (_Float16)0.f};
    float h_own = 0.f;

    for (int c = 0; c < NCH; ++c) {
        asm volatile("s_waitcnt vmcnt(0)" ::: "memory");
        __builtin_amdgcn_sched_barrier(0);
        if (c + 1 < NCH) {
            const float* src = xg + (size_t)(c + 1) * CF;
            float* dst = &xlds[(c + 1) & 1][0];
#pragma unroll
            for (int k = 0; k < 9; ++k) gload4(src + k * 64 + j, dst + k * 64);
        }
        const float* xc = &xlds[c & 1][0];

#pragma unroll 2
        for (int s = 0; s < CSTEPS; ++s) {
            const float* xs = xc + s * CC;
            float xv[CC];
#pragma unroll
            for (int cc = 0; cc < CC; ++cc) xv[cc] = xs[cc];

            // x-part (f32): init with biases
            v2f axr = (v2f){br,  0.f};
            v2f axz = (v2f){bz,  0.f};
            v2f axn = (v2f){bni, 0.f};
#pragma unroll
            for (int p = 0; p < 4; ++p) {
                v2f xp2 = (v2f){xv[2*p], xv[2*p+1]};
                axr = __builtin_elementwise_fma(wri[p], xp2, axr);
                axz = __builtin_elementwise_fma(wzi[p], xp2, axz);
                axn = __builtin_elementwise_fma(wni[p], xp2, axn);
            }
            float sr = fmaf(wri8, xv[8], axr.x + axr.y);
            float sz = fmaf(wzi8, xv[8], axz.x + axz.y);
            float sn = fmaf(wni8, xv[8], axn.x + axn.y);
            float gn = bnh;

            // h-part: fp16 dot2 with f32 accumulation
#pragma unroll
            for (int k = 0; k < 18; ++k) {
                sr = __builtin_amdgcn_fdot2(wrh[k], h2[k], sr, false);
                sz = __builtin_amdgcn_fdot2(wzh[k], h2[k], sz, false);
                gn = __builtin_amdgcn_fdot2(wnh[k], h2[k], gn, false);
            }

            float r = __builtin_amdgcn_rcpf(1.f + __expf(-sr));
            float z = __builtin_amdgcn_rcpf(1.f + __expf(-sz));
            float a = sn + r * gn;
            float n = 1.f - 2.f * __builtin_amdgcn_rcpf(__expf(2.f * a) + 1.f);
            h_own = z * (h_own - n) + n;

            // broadcast h_t: unconditional scalar f16 write (64-wide buffer,
            // lanes >= 36 write pad), then packed reads. 1-wave block: per-wave
            // DS ordering, no barrier.
            hbuf16[j] = (_Float16)h_own;
            {
#pragma unroll
                for (int q = 0; q < 4; ++q) {
                    uint4 t4 = ((const uint4*)hbuf16)[q];
                    h2[4*q+0] = __builtin_bit_cast(v2h, t4.x);
                    h2[4*q+1] = __builtin_bit_cast(v2h, t4.y);
                    h2[4*q+2] = __builtin_bit_cast(v2h, t4.z);
                    h2[4*q+3] = __builtin_bit_cast(v2h, t4.w);
                }
                uint2 t2 = ((const uint2*)hbuf16)[8];
                h2[16] = __builtin_bit_cast(v2h, t2.x);
                h2[17] = __builtin_bit_cast(v2h, t2.y);
            }
        }
    }

    // head: out[b] = sum_j h[j] * w_head[j] + b_head
    float whead = (j < HH) ? w_head[j] : 0.f;
    float v = (j < HH) ? h_own * whead : 0.f;
#pragma unroll
    for (int off = 32; off; off >>= 1) v += __shfl_down(v, off);
    if (j == 0) out[b] = v + b_head[0];
}

extern "C" void kernel_launch(void* const* d_in, const int* in_sizes, int n_in,
                              void* d_out, int out_size, void* d_ws, size_t ws_size,
                              hipStream_t stream) {
    const float* x      = (const float*)d_in[0];
    const float* w_ih   = (const float*)d_in[1];
    const float* w_hh   = (const float*)d_in[2];
    const float* b_ih   = (const float*)d_in[3];
    const float* b_hh   = (const float*)d_in[4];
    const float* w_head = (const float*)d_in[5];
    const float* b_head = (const float*)d_in[6];
    float* out = (float*)d_out;

    gru_kernel<<<BB, 64, 0, stream>>>(x, w_ih, w_hh, b_ih, b_hh,
                                      w_head, b_head, out);
}